// Round 13
// baseline (249.528 us; speedup 1.0000x reference)
//
#include <hip/hip_runtime.h>

using f16 = _Float16;
typedef _Float16 h8 __attribute__((ext_vector_type(8)));
typedef _Float16 h4 __attribute__((ext_vector_type(4)));
typedef float f32x4 __attribute__((ext_vector_type(4)));
typedef float f32x16 __attribute__((ext_vector_type(16)));
typedef unsigned u32x4 __attribute__((ext_vector_type(4)));

constexpr int L_SEQ  = 2048;
constexpr int NBATCH = 4;
constexpr int EMB    = 1024;
constexpr int NHEAD  = 16;
constexpr int HDIM   = 64;
constexpr int BH     = NBATCH * NHEAD;   // 64 head-batches
constexpr int MROWS  = L_SEQ * NBATCH;   // 8192

// Q pre-scale: 1/sqrt(HD) * log2(e)  (softmax done in exp2 domain)
#define QSCALE (0.125f * 1.44269504088896341f)

__device__ __forceinline__ void glds16(const void* g, void* l) {
  __builtin_amdgcn_global_load_lds(
      (const __attribute__((address_space(1))) void*)g,
      (__attribute__((address_space(3))) void*)l, 16, 0, 0);
}

__device__ __forceinline__ f32x16 MFMA32(h8 a, h8 b, f32x16 c) {
  return __builtin_amdgcn_mfma_f32_32x32x16_f16(a, b, c, 0, 0, 0);
}
__device__ __forceinline__ unsigned pkrtz(float x, float y) {
  auto t = __builtin_amdgcn_cvt_pkrtz(x, y);   // __fp16 ext_vector(2)
  return __builtin_bit_cast(unsigned, t);
}

// ---------------- f32 -> f16 convert (weights only now) ----------------
__global__ __launch_bounds__(256)
void convert_w_kernel(const float* __restrict__ w, const float* __restrict__ wo,
                      f16* __restrict__ wb, f16* __restrict__ wob) {
  const int NW  = 3 * EMB * EMB / 4;
  const int NWO = EMB * EMB / 4;
  const int total = NW + NWO;
  int i = blockIdx.x * blockDim.x + threadIdx.x;
  const int stride = gridDim.x * blockDim.x;
  for (; i < total; i += stride) {
    const float* s; f16* d; int j;
    if (i < NW) { s = w;  d = wb;  j = i;      }
    else        { s = wo; d = wob; j = i - NW; }
    float4 t = reinterpret_cast<const float4*>(s)[j];
    h4 o = { (f16)t.x, (f16)t.y, (f16)t.z, (f16)t.w };
    reinterpret_cast<h4*>(d)[j] = o;
  }
}

// ---------------- in-proj GEMM reading A directly in f32 ----------------
// C = A_f32 @ W^T + bias, epilogue scatters f16 into head layout.
// A staged as f32 into slot-swizzled LDS (glds16), fragments packed f16 in-reg.
__global__ __launch_bounds__(256)
void gemm_qkv(const float* __restrict__ qin, const float* __restrict__ kin,
              const float* __restrict__ vin, const f16* __restrict__ Btbase,
              const float* __restrict__ biasbase, f16* __restrict__ Hbase)
{
  const int z = blockIdx.z;
  const float* A = (z == 0) ? qin : (z == 1) ? kin : vin;
  const f16* Bt = Btbase + (size_t)z * EMB * EMB;
  const float* bias = biasbase + (size_t)z * EMB;

  const int bm = blockIdx.y * 128;
  const int bn = blockIdx.x * 128;
  const int t = threadIdx.x;
  const int w = t >> 6, lane = t & 63;
  const int wr = w >> 1, wc = w & 1;
  const int l16 = lane & 15, g = lane >> 4;

  __shared__ float Asf[128 * 32];   // 16 KB, slot-XOR swizzled
  __shared__ f16 Bs[128][32];       // 8 KB

  f32x4 acc[4][4] = {};

  // A staging: wave w covers rows [w*32, w*32+32) in four 8-row issues.
  // lane -> row lane>>3 within issue; 16B slot (lane&7) XOR row for swizzle.
  const int srow8 = lane >> 3;                  // 0..7
  const int sslot = (lane & 7) ^ srow8;         // pre-swizzled source slot
  const float* gA = &A[(size_t)(bm + w*32 + srow8) * EMB + sslot * 4];

  // B staging: as before (f16), wave w covers rows [w*32, w*32+32)
  const int sr  = lane >> 2;
  const int sc8 = (lane & 3) * 8;
  const f16* gB = &Bt[(size_t)(bn + w*32 + sr) * EMB + sc8];
  f16* lB0 = &Bs[w*32][0];
  f16* lB1 = &Bs[w*32 + 16][0];

  for (int k0 = 0; k0 < EMB; k0 += 32) {
    __syncthreads();
#pragma unroll
    for (int r = 0; r < 4; ++r)
      glds16(gA + (size_t)r*8*EMB + k0, &Asf[(w*32 + r*8) * 32]);
    glds16(gB + k0, lB0);
    glds16(gB + (size_t)16*EMB + k0, lB1);
    __syncthreads();

    h8 af[4], bfr[4];
#pragma unroll
    for (int m = 0; m < 4; ++m) {
      const int row = wr*64 + m*16 + l16;
      const int r7 = row & 7;
      f32x4 lo = *(const f32x4*)&Asf[row*32 + (((g*2    ) ^ r7) << 2)];
      f32x4 hi = *(const f32x4*)&Asf[row*32 + (((g*2 + 1) ^ r7) << 2)];
      u32x4 u = { pkrtz(lo[0], lo[1]), pkrtz(lo[2], lo[3]),
                  pkrtz(hi[0], hi[1]), pkrtz(hi[2], hi[3]) };
      af[m] = __builtin_bit_cast(h8, u);
    }
#pragma unroll
    for (int n = 0; n < 4; ++n) bfr[n] = *(const h8*)&Bs[wc*64 + n*16 + l16][g*8];
    __builtin_amdgcn_s_setprio(1);
#pragma unroll
    for (int m = 0; m < 4; ++m)
#pragma unroll
      for (int n = 0; n < 4; ++n)
        acc[m][n] = __builtin_amdgcn_mfma_f32_16x16x32_f16(af[m], bfr[n], acc[m][n], 0, 0, 0);
    __builtin_amdgcn_s_setprio(0);
  }

#pragma unroll
  for (int m = 0; m < 4; ++m) {
#pragma unroll
    for (int n = 0; n < 4; ++n) {
      const int col = bn + wc*64 + n*16 + l16;
      const float bv = bias[col];
#pragma unroll
      for (int r = 0; r < 4; ++r) {
        const int row = bm + wr*64 + m*16 + g*4 + r;
        float v = acc[m][n][r] + bv;
        if (z == 0) v *= QSCALE;
        const int l = row >> 2, nn = row & 3;
        const int h = col >> 6, hd = col & 63;
        Hbase[(((size_t)z * BH + nn * NHEAD + h) * L_SEQ + l) * HDIM + hd] = (f16)v;
      }
    }
  }
}

// ---------------- out-proj GEMM (f16 A from LDS, unchanged) ----------------
__global__ __launch_bounds__(256)
void gemm_out(const f16* __restrict__ A, const f16* __restrict__ Bt,
              const float* __restrict__ bias, float* __restrict__ Fout)
{
  const int bm = blockIdx.y * 128;
  const int bn = blockIdx.x * 128;
  const int t = threadIdx.x;
  const int w = t >> 6, lane = t & 63;
  const int wr = w >> 1, wc = w & 1;
  const int l16 = lane & 15, g = lane >> 4;

  __shared__ f16 As[128][32];
  __shared__ f16 Bs[128][32];

  f32x4 acc[4][4] = {};

  const int sr  = lane >> 2;
  const int sc8 = (lane & 3) * 8;
  const f16* gA = &A [(size_t)(bm + w*32 + sr) * EMB + sc8];
  const f16* gB = &Bt[(size_t)(bn + w*32 + sr) * EMB + sc8];
  f16* lA0 = &As[w*32][0];
  f16* lA1 = &As[w*32 + 16][0];
  f16* lB0 = &Bs[w*32][0];
  f16* lB1 = &Bs[w*32 + 16][0];

  for (int k0 = 0; k0 < EMB; k0 += 32) {
    __syncthreads();
    glds16(gA + k0, lA0);
    glds16(gA + (size_t)16*EMB + k0, lA1);
    glds16(gB + k0, lB0);
    glds16(gB + (size_t)16*EMB + k0, lB1);
    __syncthreads();

    h8 af[4], bfr[4];
#pragma unroll
    for (int m = 0; m < 4; ++m) af[m]  = *(const h8*)&As[wr*64 + m*16 + l16][g*8];
#pragma unroll
    for (int n = 0; n < 4; ++n) bfr[n] = *(const h8*)&Bs[wc*64 + n*16 + l16][g*8];
    __builtin_amdgcn_s_setprio(1);
#pragma unroll
    for (int m = 0; m < 4; ++m)
#pragma unroll
      for (int n = 0; n < 4; ++n)
        acc[m][n] = __builtin_amdgcn_mfma_f32_16x16x32_f16(af[m], bfr[n], acc[m][n], 0, 0, 0);
    __builtin_amdgcn_s_setprio(0);
  }

#pragma unroll
  for (int m = 0; m < 4; ++m) {
#pragma unroll
    for (int n = 0; n < 4; ++n) {
      const int col = bn + wc*64 + n*16 + l16;
      const float bv = bias[col];
#pragma unroll
      for (int r = 0; r < 4; ++r) {
        const int row = bm + wr*64 + m*16 + g*4 + r;
        Fout[(size_t)row * EMB + col] = acc[m][n][r] + bv;
      }
    }
  }
}

// ---------------- V transpose: [BH][L][HD] -> [BH][HD][L] ----------------
__global__ __launch_bounds__(256)
void vtrans_kernel(const f16* __restrict__ V, f16* __restrict__ Vt) {
  const int b = blockIdx.y;
  const int t = threadIdx.x;
  const int d = t & 63;
  const int l0 = (blockIdx.x * 4 + (t >> 6)) * 8;
  const f16* Vb = V  + (size_t)b * L_SEQ * HDIM;
  f16* Vtb      = Vt + (size_t)b * L_SEQ * HDIM;
  h8 v;
#pragma unroll
  for (int i = 0; i < 8; ++i) v[i] = Vb[(size_t)(l0 + i) * HDIM + d];
  *(h8*)&Vtb[(size_t)d * L_SEQ + l0] = v;
}

// ---------------- Flash attention v11 (register-slim, unchanged from R12) ----------------
__device__ __forceinline__ void attn11_step(
    const f16* __restrict__ Kc, const f16* __restrict__ Vc,
    const h8 (&qf)[4],
    f32x16 (&o)[2], float (&psum)[4],
    int l31, int hi)
{
  const int swz = (l31 & 7) << 3;

  h8 pa[4];
#pragma unroll
  for (int kt = 0; kt < 2; ++kt) {
    f32x16 acc = {};
    __builtin_amdgcn_s_setprio(1);
#pragma unroll
    for (int s = 0; s < 4; ++s) {
      h8 kf = *(const h8*)&Kc[(kt*32 + l31)*64 + ((s*16 + hi*8) ^ swz)];
      acc = MFMA32(kf, qf[s], acc);
    }
    __builtin_amdgcn_s_setprio(0);

#pragma unroll
    for (int half = 0; half < 2; ++half) {
      float p0 = __builtin_amdgcn_exp2f(acc[half*8+0]);
      float p1 = __builtin_amdgcn_exp2f(acc[half*8+1]);
      float p2 = __builtin_amdgcn_exp2f(acc[half*8+2]);
      float p3 = __builtin_amdgcn_exp2f(acc[half*8+3]);
      float p4 = __builtin_amdgcn_exp2f(acc[half*8+4]);
      float p5 = __builtin_amdgcn_exp2f(acc[half*8+5]);
      float p6 = __builtin_amdgcn_exp2f(acc[half*8+6]);
      float p7 = __builtin_amdgcn_exp2f(acc[half*8+7]);
      psum[0] += p0 + p4;
      psum[1] += p1 + p5;
      psum[2] += p2 + p6;
      psum[3] += p3 + p7;
      unsigned A = pkrtz(p0, p1);
      unsigned C = pkrtz(p2, p3);
      unsigned B = pkrtz(p4, p5);
      unsigned D = pkrtz(p6, p7);
      asm("v_permlane32_swap_b32 %0, %1" : "+v"(A), "+v"(B));
      asm("v_permlane32_swap_b32 %0, %1" : "+v"(C), "+v"(D));
      u32x4 wv = { A, C, B, D };
      pa[kt*2 + half] = __builtin_bit_cast(h8, wv);
    }
  }

#pragma unroll
  for (int s2 = 0; s2 < 4; ++s2) {
    h8 vf0 = *(const h8*)&Vc[(0*32 + l31)*64 + ((s2*16 + hi*8) ^ swz)];
    h8 vf1 = *(const h8*)&Vc[(1*32 + l31)*64 + ((s2*16 + hi*8) ^ swz)];
    __builtin_amdgcn_s_setprio(1);
    o[0] = MFMA32(pa[s2], vf0, o[0]);
    o[1] = MFMA32(pa[s2], vf1, o[1]);
    __builtin_amdgcn_s_setprio(0);
  }
}

__global__ __launch_bounds__(256, 4)
void attn11_kernel(const f16* __restrict__ Qh, const f16* __restrict__ Kh,
                   const f16* __restrict__ Vt, f16* __restrict__ AO)
{
  const int id = blockIdx.x;
  const int b    = (id & 7) | ((id >> 7) << 3);
  const int qblk = (id >> 3) & 15;

  const int t = threadIdx.x;
  const int w = t >> 6, lane = t & 63;
  const int l31 = lane & 31, hi = lane >> 5;

  const f16* Qb = Qh + (size_t)b * L_SEQ * HDIM;
  const f16* Kb = Kh + (size_t)b * L_SEQ * HDIM;
  const f16* Vb = Vt + (size_t)b * (size_t)HDIM * L_SEQ;

  __shared__ f16 Ks[2][64*64];
  __shared__ f16 Vs[2][64*64];

  const int q0 = qblk * 128 + w * 32;

  h8 qf[4];
#pragma unroll
  for (int s = 0; s < 4; ++s)
    qf[s] = *(const h8*)&Qb[(size_t)(q0 + l31) * HDIM + s*16 + hi*8];

  const int srow = lane >> 3;
  const int scol = 8 * ((lane & 7) ^ srow);
  const int r0   = w*16 + srow;
  const f16* gK0 = Kb + (size_t)(r0    ) * HDIM + scol;
  const f16* gK1 = Kb + (size_t)(r0 + 8) * HDIM + scol;
  const f16* gV0 = Vb + (size_t)(r0    ) * L_SEQ + scol;
  const f16* gV1 = Vb + (size_t)(r0 + 8) * L_SEQ + scol;
  const int ldsw = w * 1024;

  f32x16 o[2] = {};
  float psum[4] = { 0.f, 0.f, 0.f, 0.f };

  glds16(gK0, &Ks[0][ldsw]);
  glds16(gK1, &Ks[0][ldsw + 512]);
  glds16(gV0, &Vs[0][ldsw]);
  glds16(gV1, &Vs[0][ldsw + 512]);
  __syncthreads();

#pragma unroll 1
  for (int j0 = 0; j0 < L_SEQ; j0 += 128) {
    {
      const int jn = (j0 + 64) & (L_SEQ - 1);
      glds16(gK0 + (size_t)jn * HDIM, &Ks[1][ldsw]);
      glds16(gK1 + (size_t)jn * HDIM, &Ks[1][ldsw + 512]);
      glds16(gV0 + jn, &Vs[1][ldsw]);
      glds16(gV1 + jn, &Vs[1][ldsw + 512]);
      attn11_step(&Ks[0][0], &Vs[0][0], qf, o, psum, l31, hi);
      __syncthreads();
    }
    {
      const int jn = (j0 + 128) & (L_SEQ - 1);
      glds16(gK0 + (size_t)jn * HDIM, &Ks[0][ldsw]);
      glds16(gK1 + (size_t)jn * HDIM, &Ks[0][ldsw + 512]);
      glds16(gV0 + jn, &Vs[0][ldsw]);
      glds16(gV1 + jn, &Vs[0][ldsw + 512]);
      attn11_step(&Ks[1][0], &Vs[1][0], qf, o, psum, l31, hi);
      __syncthreads();
    }
  }

  float ssum = (psum[0] + psum[1]) + (psum[2] + psum[3]);
  ssum += __shfl_xor(ssum, 32);
  const float inv = 1.0f / ssum;

  const int nn = b >> 4, h = b & 15;
#pragma unroll
  for (int r = 0; r < 16; ++r) {
    const int qrow = (r & 3) + 8 * (r >> 2) + 4 * hi;
    const float iv = __shfl(inv, qrow);
    const int lr = q0 + qrow;
#pragma unroll
    for (int dt = 0; dt < 2; ++dt)
      AO[((size_t)lr * NBATCH + nn) * EMB + h*HDIM + dt*32 + l31] =
          (f16)(o[dt][r] * iv);
  }
}

// ---------------- launch ----------------
extern "C" void kernel_launch(void* const* d_in, const int* in_sizes, int n_in,
                              void* d_out, int out_size, void* d_ws, size_t ws_size,
                              hipStream_t stream) {
  const float* query = (const float*)d_in[0];
  const float* key   = (const float*)d_in[1];
  const float* value = (const float*)d_in[2];
  const float* in_w  = (const float*)d_in[3];
  const float* in_b  = (const float*)d_in[4];
  const float* out_w = (const float*)d_in[5];
  const float* out_b = (const float*)d_in[6];
  float* out = (float*)d_out;

  char* ws = (char*)d_ws;
  size_t offH  = 0;
  size_t offX  = offH  + (size_t)3 * BH * L_SEQ * HDIM * 2;
  size_t offW  = offX  + (size_t)3 * MROWS * EMB * 2;
  size_t offWo = offW  + (size_t)3 * EMB * EMB * 2;
  size_t offAO = offWo + (size_t)EMB * EMB * 2;
  f16* Hbase = (f16*)(ws + offH);
  f16* Xb    = (f16*)(ws + offX);   // q/k/v slots now unused; region reused for Vt
  f16* Wb    = (f16*)(ws + offW);
  f16* Wob   = (f16*)(ws + offWo);
  f16* AOb   = (f16*)(ws + offAO);
  f16* Vtb   = Xb;

  hipLaunchKernelGGL(convert_w_kernel, dim3(1024), dim3(256), 0, stream,
                     in_w, out_w, Wb, Wob);

  hipLaunchKernelGGL(gemm_qkv, dim3(EMB/128, MROWS/128, 3), dim3(256), 0, stream,
                     query, key, value, Wb, in_b, Hbase);

  f16* Vh = Hbase + (size_t)2 * BH * L_SEQ * HDIM;
  hipLaunchKernelGGL(vtrans_kernel, dim3(L_SEQ/32, BH), dim3(256), 0, stream, Vh, Vtb);

  hipLaunchKernelGGL(attn11_kernel, dim3(L_SEQ/128 * BH), dim3(256), 0, stream,
                     Hbase,
                     Hbase + (size_t)BH * L_SEQ * HDIM,
                     Vtb, AOb);

  hipLaunchKernelGGL(gemm_out, dim3(EMB/128, MROWS/128, 1), dim3(256), 0, stream,
                     AOb, Wob, out_b, out);
}

// Round 14
// 224.360 us; speedup vs baseline: 1.1122x; 1.1122x over previous
//
#include <hip/hip_runtime.h>

using f16 = _Float16;
typedef _Float16 h8 __attribute__((ext_vector_type(8)));
typedef _Float16 h4 __attribute__((ext_vector_type(4)));
typedef float f32x4 __attribute__((ext_vector_type(4)));
typedef float f32x16 __attribute__((ext_vector_type(16)));
typedef unsigned u32x4 __attribute__((ext_vector_type(4)));

constexpr int L_SEQ  = 2048;
constexpr int NBATCH = 4;
constexpr int EMB    = 1024;
constexpr int NHEAD  = 16;
constexpr int HDIM   = 64;
constexpr int BH     = NBATCH * NHEAD;   // 64 head-batches
constexpr int MROWS  = L_SEQ * NBATCH;   // 8192

// Q pre-scale: 1/sqrt(HD) * log2(e)  (softmax done in exp2 domain)
#define QSCALE (0.125f * 1.44269504088896341f)

__device__ __forceinline__ void glds16(const void* g, void* l) {
  __builtin_amdgcn_global_load_lds(
      (const __attribute__((address_space(1))) void*)g,
      (__attribute__((address_space(3))) void*)l, 16, 0, 0);
}

__device__ __forceinline__ f32x16 MFMA32(h8 a, h8 b, f32x16 c) {
  return __builtin_amdgcn_mfma_f32_32x32x16_f16(a, b, c, 0, 0, 0);
}
__device__ __forceinline__ unsigned pkrtz(float x, float y) {
  auto t = __builtin_amdgcn_cvt_pkrtz(x, y);   // __fp16 ext_vector(2)
  return __builtin_bit_cast(unsigned, t);
}

// ---------------- f32 -> f16 convert (weights only) ----------------
__global__ __launch_bounds__(256)
void convert_w_kernel(const float* __restrict__ w, const float* __restrict__ wo,
                      f16* __restrict__ wb, f16* __restrict__ wob) {
  const int NW  = 3 * EMB * EMB / 4;
  const int NWO = EMB * EMB / 4;
  const int total = NW + NWO;
  int i = blockIdx.x * blockDim.x + threadIdx.x;
  const int stride = gridDim.x * blockDim.x;
  for (; i < total; i += stride) {
    const float* s; f16* d; int j;
    if (i < NW) { s = w;  d = wb;  j = i;      }
    else        { s = wo; d = wob; j = i - NW; }
    float4 t = reinterpret_cast<const float4*>(s)[j];
    h4 o = { (f16)t.x, (f16)t.y, (f16)t.z, (f16)t.w };
    reinterpret_cast<h4*>(d)[j] = o;
  }
}

// ---------------- in-proj GEMM reading A directly in f32 ----------------
// 1D grid, XCD-aware mapping: XCD owns row-panels; its 8 bn-tiles run
// consecutively so the 512KB f32 A-panel stays L2-resident across reuse.
__global__ __launch_bounds__(256)
void gemm_qkv(const float* __restrict__ qin, const float* __restrict__ kin,
              const float* __restrict__ vin, const f16* __restrict__ Btbase,
              const float* __restrict__ biasbase, f16* __restrict__ Hbase)
{
  const int id = blockIdx.x;
  const int x   = id & 7;            // XCD (dispatch round-robin)
  const int bnI = (id >> 3) & 7;     // column tile, varies fastest per XCD
  const int bmG = x + 8 * (id >> 6); // global row panel 0..191 (same XCD -> same x)
  const int z   = bmG >> 6;          // 0..2 (q/k/v)
  const int bm  = (bmG & 63) * 128;
  const int bn  = bnI * 128;

  const float* A = (z == 0) ? qin : (z == 1) ? kin : vin;
  const f16* Bt = Btbase + (size_t)z * EMB * EMB;
  const float* bias = biasbase + (size_t)z * EMB;

  const int t = threadIdx.x;
  const int w = t >> 6, lane = t & 63;
  const int wr = w >> 1, wc = w & 1;
  const int l16 = lane & 15, g = lane >> 4;

  __shared__ float Asf[128 * 32];   // 16 KB, slot-XOR swizzled
  __shared__ f16 Bs[128][32];       // 8 KB

  f32x4 acc[4][4] = {};

  const int srow8 = lane >> 3;                  // 0..7
  const int sslot = (lane & 7) ^ srow8;         // pre-swizzled source slot
  const float* gA = &A[(size_t)(bm + w*32 + srow8) * EMB + sslot * 4];

  const int sr  = lane >> 2;
  const int sc8 = (lane & 3) * 8;
  const f16* gB = &Bt[(size_t)(bn + w*32 + sr) * EMB + sc8];
  f16* lB0 = &Bs[w*32][0];
  f16* lB1 = &Bs[w*32 + 16][0];

  for (int k0 = 0; k0 < EMB; k0 += 32) {
    __syncthreads();
#pragma unroll
    for (int r = 0; r < 4; ++r)
      glds16(gA + (size_t)r*8*EMB + k0, &Asf[(w*32 + r*8) * 32]);
    glds16(gB + k0, lB0);
    glds16(gB + (size_t)16*EMB + k0, lB1);
    __syncthreads();

    h8 af[4], bfr[4];
#pragma unroll
    for (int m = 0; m < 4; ++m) {
      const int row = wr*64 + m*16 + l16;
      const int r7 = row & 7;
      f32x4 lo = *(const f32x4*)&Asf[row*32 + (((g*2    ) ^ r7) << 2)];
      f32x4 hi = *(const f32x4*)&Asf[row*32 + (((g*2 + 1) ^ r7) << 2)];
      u32x4 u = { pkrtz(lo[0], lo[1]), pkrtz(lo[2], lo[3]),
                  pkrtz(hi[0], hi[1]), pkrtz(hi[2], hi[3]) };
      af[m] = __builtin_bit_cast(h8, u);
    }
#pragma unroll
    for (int n = 0; n < 4; ++n) bfr[n] = *(const h8*)&Bs[wc*64 + n*16 + l16][g*8];
    __builtin_amdgcn_s_setprio(1);
#pragma unroll
    for (int m = 0; m < 4; ++m)
#pragma unroll
      for (int n = 0; n < 4; ++n)
        acc[m][n] = __builtin_amdgcn_mfma_f32_16x16x32_f16(af[m], bfr[n], acc[m][n], 0, 0, 0);
    __builtin_amdgcn_s_setprio(0);
  }

#pragma unroll
  for (int m = 0; m < 4; ++m) {
#pragma unroll
    for (int n = 0; n < 4; ++n) {
      const int col = bn + wc*64 + n*16 + l16;
      const float bv = bias[col];
#pragma unroll
      for (int r = 0; r < 4; ++r) {
        const int row = bm + wr*64 + m*16 + g*4 + r;
        float v = acc[m][n][r] + bv;
        if (z == 0) v *= QSCALE;
        const int l = row >> 2, nn = row & 3;
        const int h = col >> 6, hd = col & 63;
        Hbase[(((size_t)z * BH + nn * NHEAD + h) * L_SEQ + l) * HDIM + hd] = (f16)v;
      }
    }
  }
}

// ---------------- out-proj GEMM (f16 A), same XCD row-panel mapping ----------------
__global__ __launch_bounds__(256)
void gemm_out(const f16* __restrict__ A, const f16* __restrict__ Bt,
              const float* __restrict__ bias, float* __restrict__ Fout)
{
  const int id = blockIdx.x;
  const int x   = id & 7;
  const int bnI = (id >> 3) & 7;
  const int bmG = x + 8 * (id >> 6);   // 0..63
  const int bm  = bmG * 128;
  const int bn  = bnI * 128;

  const int t = threadIdx.x;
  const int w = t >> 6, lane = t & 63;
  const int wr = w >> 1, wc = w & 1;
  const int l16 = lane & 15, g = lane >> 4;

  __shared__ f16 As[128][32];
  __shared__ f16 Bs[128][32];

  f32x4 acc[4][4] = {};

  const int sr  = lane >> 2;
  const int sc8 = (lane & 3) * 8;
  const f16* gA = &A [(size_t)(bm + w*32 + sr) * EMB + sc8];
  const f16* gB = &Bt[(size_t)(bn + w*32 + sr) * EMB + sc8];
  f16* lA0 = &As[w*32][0];
  f16* lA1 = &As[w*32 + 16][0];
  f16* lB0 = &Bs[w*32][0];
  f16* lB1 = &Bs[w*32 + 16][0];

  for (int k0 = 0; k0 < EMB; k0 += 32) {
    __syncthreads();
    glds16(gA + k0, lA0);
    glds16(gA + (size_t)16*EMB + k0, lA1);
    glds16(gB + k0, lB0);
    glds16(gB + (size_t)16*EMB + k0, lB1);
    __syncthreads();

    h8 af[4], bfr[4];
#pragma unroll
    for (int m = 0; m < 4; ++m) af[m]  = *(const h8*)&As[wr*64 + m*16 + l16][g*8];
#pragma unroll
    for (int n = 0; n < 4; ++n) bfr[n] = *(const h8*)&Bs[wc*64 + n*16 + l16][g*8];
    __builtin_amdgcn_s_setprio(1);
#pragma unroll
    for (int m = 0; m < 4; ++m)
#pragma unroll
      for (int n = 0; n < 4; ++n)
        acc[m][n] = __builtin_amdgcn_mfma_f32_16x16x32_f16(af[m], bfr[n], acc[m][n], 0, 0, 0);
    __builtin_amdgcn_s_setprio(0);
  }

#pragma unroll
  for (int m = 0; m < 4; ++m) {
#pragma unroll
    for (int n = 0; n < 4; ++n) {
      const int col = bn + wc*64 + n*16 + l16;
      const float bv = bias[col];
#pragma unroll
      for (int r = 0; r < 4; ++r) {
        const int row = bm + wr*64 + m*16 + g*4 + r;
        Fout[(size_t)row * EMB + col] = acc[m][n][r] + bv;
      }
    }
  }
}

// ---------------- V transpose: [BH][L][HD] -> [BH][HD][L] ----------------
__global__ __launch_bounds__(256)
void vtrans_kernel(const f16* __restrict__ V, f16* __restrict__ Vt) {
  const int b = blockIdx.y;
  const int t = threadIdx.x;
  const int d = t & 63;
  const int l0 = (blockIdx.x * 4 + (t >> 6)) * 8;
  const f16* Vb = V  + (size_t)b * L_SEQ * HDIM;
  f16* Vtb      = Vt + (size_t)b * L_SEQ * HDIM;
  h8 v;
#pragma unroll
  for (int i = 0; i < 8; ++i) v[i] = Vb[(size_t)(l0 + i) * HDIM + d];
  *(h8*)&Vtb[(size_t)d * L_SEQ + l0] = v;
}

// ---------------- Flash attention v11 (register-slim, unchanged) ----------------
__device__ __forceinline__ void attn11_step(
    const f16* __restrict__ Kc, const f16* __restrict__ Vc,
    const h8 (&qf)[4],
    f32x16 (&o)[2], float (&psum)[4],
    int l31, int hi)
{
  const int swz = (l31 & 7) << 3;

  h8 pa[4];
#pragma unroll
  for (int kt = 0; kt < 2; ++kt) {
    f32x16 acc = {};
    __builtin_amdgcn_s_setprio(1);
#pragma unroll
    for (int s = 0; s < 4; ++s) {
      h8 kf = *(const h8*)&Kc[(kt*32 + l31)*64 + ((s*16 + hi*8) ^ swz)];
      acc = MFMA32(kf, qf[s], acc);
    }
    __builtin_amdgcn_s_setprio(0);

#pragma unroll
    for (int half = 0; half < 2; ++half) {
      float p0 = __builtin_amdgcn_exp2f(acc[half*8+0]);
      float p1 = __builtin_amdgcn_exp2f(acc[half*8+1]);
      float p2 = __builtin_amdgcn_exp2f(acc[half*8+2]);
      float p3 = __builtin_amdgcn_exp2f(acc[half*8+3]);
      float p4 = __builtin_amdgcn_exp2f(acc[half*8+4]);
      float p5 = __builtin_amdgcn_exp2f(acc[half*8+5]);
      float p6 = __builtin_amdgcn_exp2f(acc[half*8+6]);
      float p7 = __builtin_amdgcn_exp2f(acc[half*8+7]);
      psum[0] += p0 + p4;
      psum[1] += p1 + p5;
      psum[2] += p2 + p6;
      psum[3] += p3 + p7;
      unsigned A = pkrtz(p0, p1);
      unsigned C = pkrtz(p2, p3);
      unsigned B = pkrtz(p4, p5);
      unsigned D = pkrtz(p6, p7);
      asm("v_permlane32_swap_b32 %0, %1" : "+v"(A), "+v"(B));
      asm("v_permlane32_swap_b32 %0, %1" : "+v"(C), "+v"(D));
      u32x4 wv = { A, C, B, D };
      pa[kt*2 + half] = __builtin_bit_cast(h8, wv);
    }
  }

#pragma unroll
  for (int s2 = 0; s2 < 4; ++s2) {
    h8 vf0 = *(const h8*)&Vc[(0*32 + l31)*64 + ((s2*16 + hi*8) ^ swz)];
    h8 vf1 = *(const h8*)&Vc[(1*32 + l31)*64 + ((s2*16 + hi*8) ^ swz)];
    __builtin_amdgcn_s_setprio(1);
    o[0] = MFMA32(pa[s2], vf0, o[0]);
    o[1] = MFMA32(pa[s2], vf1, o[1]);
    __builtin_amdgcn_s_setprio(0);
  }
}

__global__ __launch_bounds__(256, 4)
void attn11_kernel(const f16* __restrict__ Qh, const f16* __restrict__ Kh,
                   const f16* __restrict__ Vt, f16* __restrict__ AO)
{
  const int id = blockIdx.x;
  const int b    = (id & 7) | ((id >> 7) << 3);
  const int qblk = (id >> 3) & 15;

  const int t = threadIdx.x;
  const int w = t >> 6, lane = t & 63;
  const int l31 = lane & 31, hi = lane >> 5;

  const f16* Qb = Qh + (size_t)b * L_SEQ * HDIM;
  const f16* Kb = Kh + (size_t)b * L_SEQ * HDIM;
  const f16* Vb = Vt + (size_t)b * (size_t)HDIM * L_SEQ;

  __shared__ f16 Ks[2][64*64];
  __shared__ f16 Vs[2][64*64];

  const int q0 = qblk * 128 + w * 32;

  h8 qf[4];
#pragma unroll
  for (int s = 0; s < 4; ++s)
    qf[s] = *(const h8*)&Qb[(size_t)(q0 + l31) * HDIM + s*16 + hi*8];

  const int srow = lane >> 3;
  const int scol = 8 * ((lane & 7) ^ srow);
  const int r0   = w*16 + srow;
  const f16* gK0 = Kb + (size_t)(r0    ) * HDIM + scol;
  const f16* gK1 = Kb + (size_t)(r0 + 8) * HDIM + scol;
  const f16* gV0 = Vb + (size_t)(r0    ) * L_SEQ + scol;
  const f16* gV1 = Vb + (size_t)(r0 + 8) * L_SEQ + scol;
  const int ldsw = w * 1024;

  f32x16 o[2] = {};
  float psum[4] = { 0.f, 0.f, 0.f, 0.f };

  glds16(gK0, &Ks[0][ldsw]);
  glds16(gK1, &Ks[0][ldsw + 512]);
  glds16(gV0, &Vs[0][ldsw]);
  glds16(gV1, &Vs[0][ldsw + 512]);
  __syncthreads();

#pragma unroll 1
  for (int j0 = 0; j0 < L_SEQ; j0 += 128) {
    {
      const int jn = (j0 + 64) & (L_SEQ - 1);
      glds16(gK0 + (size_t)jn * HDIM, &Ks[1][ldsw]);
      glds16(gK1 + (size_t)jn * HDIM, &Ks[1][ldsw + 512]);
      glds16(gV0 + jn, &Vs[1][ldsw]);
      glds16(gV1 + jn, &Vs[1][ldsw + 512]);
      attn11_step(&Ks[0][0], &Vs[0][0], qf, o, psum, l31, hi);
      __syncthreads();
    }
    {
      const int jn = (j0 + 128) & (L_SEQ - 1);
      glds16(gK0 + (size_t)jn * HDIM, &Ks[0][ldsw]);
      glds16(gK1 + (size_t)jn * HDIM, &Ks[0][ldsw + 512]);
      glds16(gV0 + jn, &Vs[0][ldsw]);
      glds16(gV1 + jn, &Vs[0][ldsw + 512]);
      attn11_step(&Ks[1][0], &Vs[1][0], qf, o, psum, l31, hi);
      __syncthreads();
    }
  }

  float ssum = (psum[0] + psum[1]) + (psum[2] + psum[3]);
  ssum += __shfl_xor(ssum, 32);
  const float inv = 1.0f / ssum;

  const int nn = b >> 4, h = b & 15;
#pragma unroll
  for (int r = 0; r < 16; ++r) {
    const int qrow = (r & 3) + 8 * (r >> 2) + 4 * hi;
    const float iv = __shfl(inv, qrow);
    const int lr = q0 + qrow;
#pragma unroll
    for (int dt = 0; dt < 2; ++dt)
      AO[((size_t)lr * NBATCH + nn) * EMB + h*HDIM + dt*32 + l31] =
          (f16)(o[dt][r] * iv);
  }
}

// ---------------- launch ----------------
extern "C" void kernel_launch(void* const* d_in, const int* in_sizes, int n_in,
                              void* d_out, int out_size, void* d_ws, size_t ws_size,
                              hipStream_t stream) {
  const float* query = (const float*)d_in[0];
  const float* key   = (const float*)d_in[1];
  const float* value = (const float*)d_in[2];
  const float* in_w  = (const float*)d_in[3];
  const float* in_b  = (const float*)d_in[4];
  const float* out_w = (const float*)d_in[5];
  const float* out_b = (const float*)d_in[6];
  float* out = (float*)d_out;

  char* ws = (char*)d_ws;
  size_t offH  = 0;
  size_t offX  = offH  + (size_t)3 * BH * L_SEQ * HDIM * 2;
  size_t offW  = offX  + (size_t)3 * MROWS * EMB * 2;
  size_t offWo = offW  + (size_t)3 * EMB * EMB * 2;
  size_t offAO = offWo + (size_t)EMB * EMB * 2;
  f16* Hbase = (f16*)(ws + offH);
  f16* Xb    = (f16*)(ws + offX);
  f16* Wb    = (f16*)(ws + offW);
  f16* Wob   = (f16*)(ws + offWo);
  f16* AOb   = (f16*)(ws + offAO);
  f16* Vtb   = Xb;

  hipLaunchKernelGGL(convert_w_kernel, dim3(1024), dim3(256), 0, stream,
                     in_w, out_w, Wb, Wob);

  // 1536 blocks: XCD-aware row-panel mapping
  hipLaunchKernelGGL(gemm_qkv, dim3(1536), dim3(256), 0, stream,
                     query, key, value, Wb, in_b, Hbase);

  f16* Vh = Hbase + (size_t)2 * BH * L_SEQ * HDIM;
  hipLaunchKernelGGL(vtrans_kernel, dim3(L_SEQ/32, BH), dim3(256), 0, stream, Vh, Vtb);

  hipLaunchKernelGGL(attn11_kernel, dim3(L_SEQ/128 * BH), dim3(256), 0, stream,
                     Hbase,
                     Hbase + (size_t)BH * L_SEQ * HDIM,
                     Vtb, AOb);

  hipLaunchKernelGGL(gemm_out, dim3(512), dim3(256), 0, stream,
                     AOb, Wob, out_b, out);
}

// Round 15
// 221.081 us; speedup vs baseline: 1.1287x; 1.0148x over previous
//
#include <hip/hip_runtime.h>

using f16 = _Float16;
typedef _Float16 h8 __attribute__((ext_vector_type(8)));
typedef _Float16 h4 __attribute__((ext_vector_type(4)));
typedef float f32x4 __attribute__((ext_vector_type(4)));
typedef float f32x16 __attribute__((ext_vector_type(16)));
typedef unsigned u32x4 __attribute__((ext_vector_type(4)));

constexpr int L_SEQ  = 2048;
constexpr int NBATCH = 4;
constexpr int EMB    = 1024;
constexpr int NHEAD  = 16;
constexpr int HDIM   = 64;
constexpr int BH     = NBATCH * NHEAD;   // 64 head-batches
constexpr int MROWS  = L_SEQ * NBATCH;   // 8192

// Q pre-scale: 1/sqrt(HD) * log2(e)  (softmax done in exp2 domain)
#define QSCALE (0.125f * 1.44269504088896341f)

__device__ __forceinline__ void glds16(const void* g, void* l) {
  __builtin_amdgcn_global_load_lds(
      (const __attribute__((address_space(1))) void*)g,
      (__attribute__((address_space(3))) void*)l, 16, 0, 0);
}

__device__ __forceinline__ f32x16 MFMA32(h8 a, h8 b, f32x16 c) {
  return __builtin_amdgcn_mfma_f32_32x32x16_f16(a, b, c, 0, 0, 0);
}
__device__ __forceinline__ unsigned pkrtz(float x, float y) {
  auto t = __builtin_amdgcn_cvt_pkrtz(x, y);   // __fp16 ext_vector(2)
  return __builtin_bit_cast(unsigned, t);
}

// ---------------- f32 -> f16 convert (weights only) ----------------
__global__ __launch_bounds__(256)
void convert_w_kernel(const float* __restrict__ w, const float* __restrict__ wo,
                      f16* __restrict__ wb, f16* __restrict__ wob) {
  const int NW  = 3 * EMB * EMB / 4;
  const int NWO = EMB * EMB / 4;
  const int total = NW + NWO;
  int i = blockIdx.x * blockDim.x + threadIdx.x;
  const int stride = gridDim.x * blockDim.x;
  for (; i < total; i += stride) {
    const float* s; f16* d; int j;
    if (i < NW) { s = w;  d = wb;  j = i;      }
    else        { s = wo; d = wob; j = i - NW; }
    float4 t = reinterpret_cast<const float4*>(s)[j];
    h4 o = { (f16)t.x, (f16)t.y, (f16)t.z, (f16)t.w };
    reinterpret_cast<h4*>(d)[j] = o;
  }
}

// ---------------- in-proj GEMM, f32 A, LDS double-buffer (1 barrier/step) ----------------
__global__ __launch_bounds__(256)
void gemm_qkv(const float* __restrict__ qin, const float* __restrict__ kin,
              const float* __restrict__ vin, const f16* __restrict__ Btbase,
              const float* __restrict__ biasbase, f16* __restrict__ Hbase)
{
  const int id = blockIdx.x;
  const int x   = id & 7;            // XCD
  const int bnI = (id >> 3) & 7;     // column tile, varies fastest per XCD
  const int bmG = x + 8 * (id >> 6); // global row panel 0..191
  const int z   = bmG >> 6;          // 0..2 (q/k/v)
  const int bm  = (bmG & 63) * 128;
  const int bn  = bnI * 128;

  const float* A = (z == 0) ? qin : (z == 1) ? kin : vin;
  const f16* Bt = Btbase + (size_t)z * EMB * EMB;
  const float* bias = biasbase + (size_t)z * EMB;

  const int t = threadIdx.x;
  const int w = t >> 6, lane = t & 63;
  const int wr = w >> 1, wc = w & 1;
  const int l16 = lane & 15, g = lane >> 4;

  __shared__ float Asf[2][128 * 32];   // 2 x 16 KB, slot-XOR swizzled
  __shared__ f16 Bs[2][128][32];       // 2 x 8 KB

  f32x4 acc[4][4] = {};

  const int srow8 = lane >> 3;                  // 0..7
  const int sslot = (lane & 7) ^ srow8;         // pre-swizzled source slot
  const float* gA = &A[(size_t)(bm + w*32 + srow8) * EMB + sslot * 4];

  const int sr  = lane >> 2;
  const int sc8 = (lane & 3) * 8;
  const f16* gB = &Bt[(size_t)(bn + w*32 + sr) * EMB + sc8];

  // prologue: stage k0=0 into buf 0
#pragma unroll
  for (int r = 0; r < 4; ++r)
    glds16(gA + (size_t)r*8*EMB, &Asf[0][(w*32 + r*8) * 32]);
  glds16(gB, &Bs[0][w*32][0]);
  glds16(gB + (size_t)16*EMB, &Bs[0][w*32 + 16][0]);
  __syncthreads();

#pragma unroll 1
  for (int i = 0; i < 32; ++i) {
    const int cur = i & 1;
    if (i < 31) {
      const int k0 = (i + 1) * 32;
#pragma unroll
      for (int r = 0; r < 4; ++r)
        glds16(gA + (size_t)r*8*EMB + k0, &Asf[cur ^ 1][(w*32 + r*8) * 32]);
      glds16(gB + k0, &Bs[cur ^ 1][w*32][0]);
      glds16(gB + (size_t)16*EMB + k0, &Bs[cur ^ 1][w*32 + 16][0]);
    }

    h8 af[4], bfr[4];
#pragma unroll
    for (int m = 0; m < 4; ++m) {
      const int row = wr*64 + m*16 + l16;
      const int r7 = row & 7;
      f32x4 lo = *(const f32x4*)&Asf[cur][row*32 + (((g*2    ) ^ r7) << 2)];
      f32x4 hi = *(const f32x4*)&Asf[cur][row*32 + (((g*2 + 1) ^ r7) << 2)];
      u32x4 u = { pkrtz(lo[0], lo[1]), pkrtz(lo[2], lo[3]),
                  pkrtz(hi[0], hi[1]), pkrtz(hi[2], hi[3]) };
      af[m] = __builtin_bit_cast(h8, u);
    }
#pragma unroll
    for (int n = 0; n < 4; ++n) bfr[n] = *(const h8*)&Bs[cur][wc*64 + n*16 + l16][g*8];
    __builtin_amdgcn_s_setprio(1);
#pragma unroll
    for (int m = 0; m < 4; ++m)
#pragma unroll
      for (int n = 0; n < 4; ++n)
        acc[m][n] = __builtin_amdgcn_mfma_f32_16x16x32_f16(af[m], bfr[n], acc[m][n], 0, 0, 0);
    __builtin_amdgcn_s_setprio(0);
    __syncthreads();   // drains stage (vmcnt) + all reads of cur done
  }

#pragma unroll
  for (int m = 0; m < 4; ++m) {
#pragma unroll
    for (int n = 0; n < 4; ++n) {
      const int col = bn + wc*64 + n*16 + l16;
      const float bv = bias[col];
#pragma unroll
      for (int r = 0; r < 4; ++r) {
        const int row = bm + wr*64 + m*16 + g*4 + r;
        float v = acc[m][n][r] + bv;
        if (z == 0) v *= QSCALE;
        const int l = row >> 2, nn = row & 3;
        const int h = col >> 6, hd = col & 63;
        Hbase[(((size_t)z * BH + nn * NHEAD + h) * L_SEQ + l) * HDIM + hd] = (f16)v;
      }
    }
  }
}

// ---------------- out-proj GEMM (f16 A), double-buffered, XCD row-panels ----------------
__global__ __launch_bounds__(256)
void gemm_out(const f16* __restrict__ A, const f16* __restrict__ Bt,
              const float* __restrict__ bias, float* __restrict__ Fout)
{
  const int id = blockIdx.x;
  const int x   = id & 7;
  const int bnI = (id >> 3) & 7;
  const int bmG = x + 8 * (id >> 6);   // 0..63
  const int bm  = bmG * 128;
  const int bn  = bnI * 128;

  const int t = threadIdx.x;
  const int w = t >> 6, lane = t & 63;
  const int wr = w >> 1, wc = w & 1;
  const int l16 = lane & 15, g = lane >> 4;

  __shared__ f16 As[2][128][32];
  __shared__ f16 Bs[2][128][32];

  f32x4 acc[4][4] = {};

  const int sr  = lane >> 2;
  const int sc8 = (lane & 3) * 8;
  const f16* gA = &A [(size_t)(bm + w*32 + sr) * EMB + sc8];
  const f16* gB = &Bt[(size_t)(bn + w*32 + sr) * EMB + sc8];

  glds16(gA, &As[0][w*32][0]);
  glds16(gA + (size_t)16*EMB, &As[0][w*32 + 16][0]);
  glds16(gB, &Bs[0][w*32][0]);
  glds16(gB + (size_t)16*EMB, &Bs[0][w*32 + 16][0]);
  __syncthreads();

#pragma unroll 1
  for (int i = 0; i < 32; ++i) {
    const int cur = i & 1;
    if (i < 31) {
      const int k0 = (i + 1) * 32;
      glds16(gA + k0, &As[cur ^ 1][w*32][0]);
      glds16(gA + (size_t)16*EMB + k0, &As[cur ^ 1][w*32 + 16][0]);
      glds16(gB + k0, &Bs[cur ^ 1][w*32][0]);
      glds16(gB + (size_t)16*EMB + k0, &Bs[cur ^ 1][w*32 + 16][0]);
    }

    h8 af[4], bfr[4];
#pragma unroll
    for (int m = 0; m < 4; ++m) af[m]  = *(const h8*)&As[cur][wr*64 + m*16 + l16][g*8];
#pragma unroll
    for (int n = 0; n < 4; ++n) bfr[n] = *(const h8*)&Bs[cur][wc*64 + n*16 + l16][g*8];
    __builtin_amdgcn_s_setprio(1);
#pragma unroll
    for (int m = 0; m < 4; ++m)
#pragma unroll
      for (int n = 0; n < 4; ++n)
        acc[m][n] = __builtin_amdgcn_mfma_f32_16x16x32_f16(af[m], bfr[n], acc[m][n], 0, 0, 0);
    __builtin_amdgcn_s_setprio(0);
    __syncthreads();
  }

#pragma unroll
  for (int m = 0; m < 4; ++m) {
#pragma unroll
    for (int n = 0; n < 4; ++n) {
      const int col = bn + wc*64 + n*16 + l16;
      const float bv = bias[col];
#pragma unroll
      for (int r = 0; r < 4; ++r) {
        const int row = bm + wr*64 + m*16 + g*4 + r;
        Fout[(size_t)row * EMB + col] = acc[m][n][r] + bv;
      }
    }
  }
}

// ---------------- V transpose: [BH][L][HD] -> [BH][HD][L] ----------------
__global__ __launch_bounds__(256)
void vtrans_kernel(const f16* __restrict__ V, f16* __restrict__ Vt) {
  const int b = blockIdx.y;
  const int t = threadIdx.x;
  const int d = t & 63;
  const int l0 = (blockIdx.x * 4 + (t >> 6)) * 8;
  const f16* Vb = V  + (size_t)b * L_SEQ * HDIM;
  f16* Vtb      = Vt + (size_t)b * L_SEQ * HDIM;
  h8 v;
#pragma unroll
  for (int i = 0; i < 8; ++i) v[i] = Vb[(size_t)(l0 + i) * HDIM + d];
  *(h8*)&Vtb[(size_t)d * L_SEQ + l0] = v;
}

// ---------------- Flash attention v11 (register-slim, unchanged) ----------------
__device__ __forceinline__ void attn11_step(
    const f16* __restrict__ Kc, const f16* __restrict__ Vc,
    const h8 (&qf)[4],
    f32x16 (&o)[2], float (&psum)[4],
    int l31, int hi)
{
  const int swz = (l31 & 7) << 3;

  h8 pa[4];
#pragma unroll
  for (int kt = 0; kt < 2; ++kt) {
    f32x16 acc = {};
    __builtin_amdgcn_s_setprio(1);
#pragma unroll
    for (int s = 0; s < 4; ++s) {
      h8 kf = *(const h8*)&Kc[(kt*32 + l31)*64 + ((s*16 + hi*8) ^ swz)];
      acc = MFMA32(kf, qf[s], acc);
    }
    __builtin_amdgcn_s_setprio(0);

#pragma unroll
    for (int half = 0; half < 2; ++half) {
      float p0 = __builtin_amdgcn_exp2f(acc[half*8+0]);
      float p1 = __builtin_amdgcn_exp2f(acc[half*8+1]);
      float p2 = __builtin_amdgcn_exp2f(acc[half*8+2]);
      float p3 = __builtin_amdgcn_exp2f(acc[half*8+3]);
      float p4 = __builtin_amdgcn_exp2f(acc[half*8+4]);
      float p5 = __builtin_amdgcn_exp2f(acc[half*8+5]);
      float p6 = __builtin_amdgcn_exp2f(acc[half*8+6]);
      float p7 = __builtin_amdgcn_exp2f(acc[half*8+7]);
      psum[0] += p0 + p4;
      psum[1] += p1 + p5;
      psum[2] += p2 + p6;
      psum[3] += p3 + p7;
      unsigned A = pkrtz(p0, p1);
      unsigned C = pkrtz(p2, p3);
      unsigned B = pkrtz(p4, p5);
      unsigned D = pkrtz(p6, p7);
      asm("v_permlane32_swap_b32 %0, %1" : "+v"(A), "+v"(B));
      asm("v_permlane32_swap_b32 %0, %1" : "+v"(C), "+v"(D));
      u32x4 wv = { A, C, B, D };
      pa[kt*2 + half] = __builtin_bit_cast(h8, wv);
    }
  }

#pragma unroll
  for (int s2 = 0; s2 < 4; ++s2) {
    h8 vf0 = *(const h8*)&Vc[(0*32 + l31)*64 + ((s2*16 + hi*8) ^ swz)];
    h8 vf1 = *(const h8*)&Vc[(1*32 + l31)*64 + ((s2*16 + hi*8) ^ swz)];
    __builtin_amdgcn_s_setprio(1);
    o[0] = MFMA32(pa[s2], vf0, o[0]);
    o[1] = MFMA32(pa[s2], vf1, o[1]);
    __builtin_amdgcn_s_setprio(0);
  }
}

__global__ __launch_bounds__(256, 4)
void attn11_kernel(const f16* __restrict__ Qh, const f16* __restrict__ Kh,
                   const f16* __restrict__ Vt, f16* __restrict__ AO)
{
  const int id = blockIdx.x;
  const int b    = (id & 7) | ((id >> 7) << 3);
  const int qblk = (id >> 3) & 15;

  const int t = threadIdx.x;
  const int w = t >> 6, lane = t & 63;
  const int l31 = lane & 31, hi = lane >> 5;

  const f16* Qb = Qh + (size_t)b * L_SEQ * HDIM;
  const f16* Kb = Kh + (size_t)b * L_SEQ * HDIM;
  const f16* Vb = Vt + (size_t)b * (size_t)HDIM * L_SEQ;

  __shared__ f16 Ks[2][64*64];
  __shared__ f16 Vs[2][64*64];

  const int q0 = qblk * 128 + w * 32;

  h8 qf[4];
#pragma unroll
  for (int s = 0; s < 4; ++s)
    qf[s] = *(const h8*)&Qb[(size_t)(q0 + l31) * HDIM + s*16 + hi*8];

  const int srow = lane >> 3;
  const int scol = 8 * ((lane & 7) ^ srow);
  const int r0   = w*16 + srow;
  const f16* gK0 = Kb + (size_t)(r0    ) * HDIM + scol;
  const f16* gK1 = Kb + (size_t)(r0 + 8) * HDIM + scol;
  const f16* gV0 = Vb + (size_t)(r0    ) * L_SEQ + scol;
  const f16* gV1 = Vb + (size_t)(r0 + 8) * L_SEQ + scol;
  const int ldsw = w * 1024;

  f32x16 o[2] = {};
  float psum[4] = { 0.f, 0.f, 0.f, 0.f };

  glds16(gK0, &Ks[0][ldsw]);
  glds16(gK1, &Ks[0][ldsw + 512]);
  glds16(gV0, &Vs[0][ldsw]);
  glds16(gV1, &Vs[0][ldsw + 512]);
  __syncthreads();

#pragma unroll 1
  for (int j0 = 0; j0 < L_SEQ; j0 += 128) {
    {
      const int jn = (j0 + 64) & (L_SEQ - 1);
      glds16(gK0 + (size_t)jn * HDIM, &Ks[1][ldsw]);
      glds16(gK1 + (size_t)jn * HDIM, &Ks[1][ldsw + 512]);
      glds16(gV0 + jn, &Vs[1][ldsw]);
      glds16(gV1 + jn, &Vs[1][ldsw + 512]);
      attn11_step(&Ks[0][0], &Vs[0][0], qf, o, psum, l31, hi);
      __syncthreads();
    }
    {
      const int jn = (j0 + 128) & (L_SEQ - 1);
      glds16(gK0 + (size_t)jn * HDIM, &Ks[0][ldsw]);
      glds16(gK1 + (size_t)jn * HDIM, &Ks[0][ldsw + 512]);
      glds16(gV0 + jn, &Vs[0][ldsw]);
      glds16(gV1 + jn, &Vs[0][ldsw + 512]);
      attn11_step(&Ks[1][0], &Vs[1][0], qf, o, psum, l31, hi);
      __syncthreads();
    }
  }

  float ssum = (psum[0] + psum[1]) + (psum[2] + psum[3]);
  ssum += __shfl_xor(ssum, 32);
  const float inv = 1.0f / ssum;

  const int nn = b >> 4, h = b & 15;
#pragma unroll
  for (int r = 0; r < 16; ++r) {
    const int qrow = (r & 3) + 8 * (r >> 2) + 4 * hi;
    const float iv = __shfl(inv, qrow);
    const int lr = q0 + qrow;
#pragma unroll
    for (int dt = 0; dt < 2; ++dt)
      AO[((size_t)lr * NBATCH + nn) * EMB + h*HDIM + dt*32 + l31] =
          (f16)(o[dt][r] * iv);
  }
}

// ---------------- launch ----------------
extern "C" void kernel_launch(void* const* d_in, const int* in_sizes, int n_in,
                              void* d_out, int out_size, void* d_ws, size_t ws_size,
                              hipStream_t stream) {
  const float* query = (const float*)d_in[0];
  const float* key   = (const float*)d_in[1];
  const float* value = (const float*)d_in[2];
  const float* in_w  = (const float*)d_in[3];
  const float* in_b  = (const float*)d_in[4];
  const float* out_w = (const float*)d_in[5];
  const float* out_b = (const float*)d_in[6];
  float* out = (float*)d_out;

  char* ws = (char*)d_ws;
  size_t offH  = 0;
  size_t offX  = offH  + (size_t)3 * BH * L_SEQ * HDIM * 2;
  size_t offW  = offX  + (size_t)3 * MROWS * EMB * 2;
  size_t offWo = offW  + (size_t)3 * EMB * EMB * 2;
  size_t offAO = offWo + (size_t)EMB * EMB * 2;
  f16* Hbase = (f16*)(ws + offH);
  f16* Xb    = (f16*)(ws + offX);
  f16* Wb    = (f16*)(ws + offW);
  f16* Wob   = (f16*)(ws + offWo);
  f16* AOb   = (f16*)(ws + offAO);
  f16* Vtb   = Xb;

  hipLaunchKernelGGL(convert_w_kernel, dim3(1024), dim3(256), 0, stream,
                     in_w, out_w, Wb, Wob);

  hipLaunchKernelGGL(gemm_qkv, dim3(1536), dim3(256), 0, stream,
                     query, key, value, Wb, in_b, Hbase);

  f16* Vh = Hbase + (size_t)2 * BH * L_SEQ * HDIM;
  hipLaunchKernelGGL(vtrans_kernel, dim3(L_SEQ/32, BH), dim3(256), 0, stream, Vh, Vtb);

  hipLaunchKernelGGL(attn11_kernel, dim3(L_SEQ/128 * BH), dim3(256), 0, stream,
                     Hbase,
                     Hbase + (size_t)BH * L_SEQ * HDIM,
                     Vtb, AOb);

  hipLaunchKernelGGL(gemm_out, dim3(512), dim3(256), 0, stream,
                     AOb, Wob, out_b, out);
}

// Round 16
// 220.761 us; speedup vs baseline: 1.1303x; 1.0014x over previous
//
#include <hip/hip_runtime.h>

using f16 = _Float16;
typedef _Float16 h8 __attribute__((ext_vector_type(8)));
typedef _Float16 h4 __attribute__((ext_vector_type(4)));
typedef float f32x4 __attribute__((ext_vector_type(4)));
typedef float f32x16 __attribute__((ext_vector_type(16)));
typedef unsigned u32x4 __attribute__((ext_vector_type(4)));

constexpr int L_SEQ  = 2048;
constexpr int NBATCH = 4;
constexpr int EMB    = 1024;
constexpr int NHEAD  = 16;
constexpr int HDIM   = 64;
constexpr int BH     = NBATCH * NHEAD;   // 64 head-batches
constexpr int MROWS  = L_SEQ * NBATCH;   // 8192

// Q pre-scale: 1/sqrt(HD) * log2(e)  (softmax done in exp2 domain)
#define QSCALE (0.125f * 1.44269504088896341f)

__device__ __forceinline__ void glds16(const void* g, void* l) {
  __builtin_amdgcn_global_load_lds(
      (const __attribute__((address_space(1))) void*)g,
      (__attribute__((address_space(3))) void*)l, 16, 0, 0);
}

__device__ __forceinline__ f32x16 MFMA32(h8 a, h8 b, f32x16 c) {
  return __builtin_amdgcn_mfma_f32_32x32x16_f16(a, b, c, 0, 0, 0);
}
__device__ __forceinline__ unsigned pkrtz(float x, float y) {
  auto t = __builtin_amdgcn_cvt_pkrtz(x, y);   // __fp16 ext_vector(2)
  return __builtin_bit_cast(unsigned, t);
}

// ---------------- f32 -> f16 convert (weights only) ----------------
__global__ __launch_bounds__(256)
void convert_w_kernel(const float* __restrict__ w, const float* __restrict__ wo,
                      f16* __restrict__ wb, f16* __restrict__ wob) {
  const int NW  = 3 * EMB * EMB / 4;
  const int NWO = EMB * EMB / 4;
  const int total = NW + NWO;
  int i = blockIdx.x * blockDim.x + threadIdx.x;
  const int stride = gridDim.x * blockDim.x;
  for (; i < total; i += stride) {
    const float* s; f16* d; int j;
    if (i < NW) { s = w;  d = wb;  j = i;      }
    else        { s = wo; d = wob; j = i - NW; }
    float4 t = reinterpret_cast<const float4*>(s)[j];
    h4 o = { (f16)t.x, (f16)t.y, (f16)t.z, (f16)t.w };
    reinterpret_cast<h4*>(d)[j] = o;
  }
}

// ---------------- in-proj GEMM, f32 A, 3-stage pipeline, counted vmcnt ----------------
// Stage(i+2) issued each iter; s_waitcnt vmcnt(6) + RAW s_barrier keeps the
// next batch's loads in flight ACROSS the barrier (T3/T4). 72KB LDS.
__global__ __launch_bounds__(256)
void gemm_qkv(const float* __restrict__ qin, const float* __restrict__ kin,
              const float* __restrict__ vin, const f16* __restrict__ Btbase,
              const float* __restrict__ biasbase, f16* __restrict__ Hbase)
{
  const int id = blockIdx.x;
  const int x   = id & 7;            // XCD
  const int bnI = (id >> 3) & 7;     // column tile, varies fastest per XCD
  const int bmG = x + 8 * (id >> 6); // global row panel 0..191
  const int z   = bmG >> 6;          // 0..2 (q/k/v)
  const int bm  = (bmG & 63) * 128;
  const int bn  = bnI * 128;

  const float* A = (z == 0) ? qin : (z == 1) ? kin : vin;
  const f16* Bt = Btbase + (size_t)z * EMB * EMB;
  const float* bias = biasbase + (size_t)z * EMB;

  const int t = threadIdx.x;
  const int w = t >> 6, lane = t & 63;
  const int wr = w >> 1, wc = w & 1;
  const int l16 = lane & 15, g = lane >> 4;

  __shared__ float Asf[3][128 * 32];   // 3 x 16 KB, slot-XOR swizzled
  __shared__ f16 Bs[3][128][32];       // 3 x 8 KB

  f32x4 acc[4][4] = {};

  const int srow8 = lane >> 3;                  // 0..7
  const int sslot = (lane & 7) ^ srow8;         // pre-swizzled source slot
  const float* gA = &A[(size_t)(bm + w*32 + srow8) * EMB + sslot * 4];

  const int sr  = lane >> 2;
  const int sc8 = (lane & 3) * 8;
  const f16* gB = &Bt[(size_t)(bn + w*32 + sr) * EMB + sc8];

  auto stage = [&](int buf, int k0) {
#pragma unroll
    for (int r = 0; r < 4; ++r)
      glds16(gA + (size_t)r*8*EMB + k0, &Asf[buf][(w*32 + r*8) * 32]);
    glds16(gB + k0, &Bs[buf][w*32][0]);
    glds16(gB + (size_t)16*EMB + k0, &Bs[buf][w*32 + 16][0]);
  };

  auto compute = [&](int buf) {
    h8 af[4], bfr[4];
#pragma unroll
    for (int m = 0; m < 4; ++m) {
      const int row = wr*64 + m*16 + l16;
      const int r7 = row & 7;
      f32x4 lo = *(const f32x4*)&Asf[buf][row*32 + (((g*2    ) ^ r7) << 2)];
      f32x4 hi = *(const f32x4*)&Asf[buf][row*32 + (((g*2 + 1) ^ r7) << 2)];
      u32x4 u = { pkrtz(lo[0], lo[1]), pkrtz(lo[2], lo[3]),
                  pkrtz(hi[0], hi[1]), pkrtz(hi[2], hi[3]) };
      af[m] = __builtin_bit_cast(h8, u);
    }
#pragma unroll
    for (int n = 0; n < 4; ++n) bfr[n] = *(const h8*)&Bs[buf][wc*64 + n*16 + l16][g*8];
    __builtin_amdgcn_s_setprio(1);
#pragma unroll
    for (int m = 0; m < 4; ++m)
#pragma unroll
      for (int n = 0; n < 4; ++n)
        acc[m][n] = __builtin_amdgcn_mfma_f32_16x16x32_f16(af[m], bfr[n], acc[m][n], 0, 0, 0);
    __builtin_amdgcn_s_setprio(0);
  };

  // prologue: stage iters 0 and 1
  stage(0, 0);
  stage(1, 32);

  int cur = 0;
#pragma unroll 1
  for (int i = 0; i < 31; ++i) {
    // wait for buf[cur] (leaves the newest batch's 6 loads in flight)
    asm volatile("s_waitcnt vmcnt(6)" ::: "memory");
    __builtin_amdgcn_sched_barrier(0);
    __builtin_amdgcn_s_barrier();
    __builtin_amdgcn_sched_barrier(0);
    if (i < 30) {
      const int nb = (cur + 2 >= 3) ? cur - 1 : cur + 2;
      stage(nb, (i + 2) * 32);
    }
    compute(cur);
    cur = (cur == 2) ? 0 : cur + 1;
  }
  // final iteration: drain everything
  asm volatile("s_waitcnt vmcnt(0)" ::: "memory");
  __builtin_amdgcn_sched_barrier(0);
  __builtin_amdgcn_s_barrier();
  __builtin_amdgcn_sched_barrier(0);
  compute(cur);

#pragma unroll
  for (int m = 0; m < 4; ++m) {
#pragma unroll
    for (int n = 0; n < 4; ++n) {
      const int col = bn + wc*64 + n*16 + l16;
      const float bv = bias[col];
#pragma unroll
      for (int r = 0; r < 4; ++r) {
        const int row = bm + wr*64 + m*16 + g*4 + r;
        float v = acc[m][n][r] + bv;
        if (z == 0) v *= QSCALE;
        const int l = row >> 2, nn = row & 3;
        const int h = col >> 6, hd = col & 63;
        Hbase[(((size_t)z * BH + nn * NHEAD + h) * L_SEQ + l) * HDIM + hd] = (f16)v;
      }
    }
  }
}

// ---------------- out-proj GEMM (f16 A), double-buffered, XCD row-panels ----------------
__global__ __launch_bounds__(256)
void gemm_out(const f16* __restrict__ A, const f16* __restrict__ Bt,
              const float* __restrict__ bias, float* __restrict__ Fout)
{
  const int id = blockIdx.x;
  const int x   = id & 7;
  const int bnI = (id >> 3) & 7;
  const int bmG = x + 8 * (id >> 6);   // 0..63
  const int bm  = bmG * 128;
  const int bn  = bnI * 128;

  const int t = threadIdx.x;
  const int w = t >> 6, lane = t & 63;
  const int wr = w >> 1, wc = w & 1;
  const int l16 = lane & 15, g = lane >> 4;

  __shared__ f16 As[2][128][32];
  __shared__ f16 Bs[2][128][32];

  f32x4 acc[4][4] = {};

  const int sr  = lane >> 2;
  const int sc8 = (lane & 3) * 8;
  const f16* gA = &A [(size_t)(bm + w*32 + sr) * EMB + sc8];
  const f16* gB = &Bt[(size_t)(bn + w*32 + sr) * EMB + sc8];

  glds16(gA, &As[0][w*32][0]);
  glds16(gA + (size_t)16*EMB, &As[0][w*32 + 16][0]);
  glds16(gB, &Bs[0][w*32][0]);
  glds16(gB + (size_t)16*EMB, &Bs[0][w*32 + 16][0]);
  __syncthreads();

#pragma unroll 1
  for (int i = 0; i < 32; ++i) {
    const int cur = i & 1;
    if (i < 31) {
      const int k0 = (i + 1) * 32;
      glds16(gA + k0, &As[cur ^ 1][w*32][0]);
      glds16(gA + (size_t)16*EMB + k0, &As[cur ^ 1][w*32 + 16][0]);
      glds16(gB + k0, &Bs[cur ^ 1][w*32][0]);
      glds16(gB + (size_t)16*EMB + k0, &Bs[cur ^ 1][w*32 + 16][0]);
    }

    h8 af[4], bfr[4];
#pragma unroll
    for (int m = 0; m < 4; ++m) af[m]  = *(const h8*)&As[cur][wr*64 + m*16 + l16][g*8];
#pragma unroll
    for (int n = 0; n < 4; ++n) bfr[n] = *(const h8*)&Bs[cur][wc*64 + n*16 + l16][g*8];
    __builtin_amdgcn_s_setprio(1);
#pragma unroll
    for (int m = 0; m < 4; ++m)
#pragma unroll
      for (int n = 0; n < 4; ++n)
        acc[m][n] = __builtin_amdgcn_mfma_f32_16x16x32_f16(af[m], bfr[n], acc[m][n], 0, 0, 0);
    __builtin_amdgcn_s_setprio(0);
    __syncthreads();
  }

#pragma unroll
  for (int m = 0; m < 4; ++m) {
#pragma unroll
    for (int n = 0; n < 4; ++n) {
      const int col = bn + wc*64 + n*16 + l16;
      const float bv = bias[col];
#pragma unroll
      for (int r = 0; r < 4; ++r) {
        const int row = bm + wr*64 + m*16 + g*4 + r;
        Fout[(size_t)row * EMB + col] = acc[m][n][r] + bv;
      }
    }
  }
}

// ---------------- V transpose: [BH][L][HD] -> [BH][HD][L] ----------------
__global__ __launch_bounds__(256)
void vtrans_kernel(const f16* __restrict__ V, f16* __restrict__ Vt) {
  const int b = blockIdx.y;
  const int t = threadIdx.x;
  const int d = t & 63;
  const int l0 = (blockIdx.x * 4 + (t >> 6)) * 8;
  const f16* Vb = V  + (size_t)b * L_SEQ * HDIM;
  f16* Vtb      = Vt + (size_t)b * L_SEQ * HDIM;
  h8 v;
#pragma unroll
  for (int i = 0; i < 8; ++i) v[i] = Vb[(size_t)(l0 + i) * HDIM + d];
  *(h8*)&Vtb[(size_t)d * L_SEQ + l0] = v;
}

// ---------------- Flash attention v11 (register-slim, unchanged) ----------------
__device__ __forceinline__ void attn11_step(
    const f16* __restrict__ Kc, const f16* __restrict__ Vc,
    const h8 (&qf)[4],
    f32x16 (&o)[2], float (&psum)[4],
    int l31, int hi)
{
  const int swz = (l31 & 7) << 3;

  h8 pa[4];
#pragma unroll
  for (int kt = 0; kt < 2; ++kt) {
    f32x16 acc = {};
    __builtin_amdgcn_s_setprio(1);
#pragma unroll
    for (int s = 0; s < 4; ++s) {
      h8 kf = *(const h8*)&Kc[(kt*32 + l31)*64 + ((s*16 + hi*8) ^ swz)];
      acc = MFMA32(kf, qf[s], acc);
    }
    __builtin_amdgcn_s_setprio(0);

#pragma unroll
    for (int half = 0; half < 2; ++half) {
      float p0 = __builtin_amdgcn_exp2f(acc[half*8+0]);
      float p1 = __builtin_amdgcn_exp2f(acc[half*8+1]);
      float p2 = __builtin_amdgcn_exp2f(acc[half*8+2]);
      float p3 = __builtin_amdgcn_exp2f(acc[half*8+3]);
      float p4 = __builtin_amdgcn_exp2f(acc[half*8+4]);
      float p5 = __builtin_amdgcn_exp2f(acc[half*8+5]);
      float p6 = __builtin_amdgcn_exp2f(acc[half*8+6]);
      float p7 = __builtin_amdgcn_exp2f(acc[half*8+7]);
      psum[0] += p0 + p4;
      psum[1] += p1 + p5;
      psum[2] += p2 + p6;
      psum[3] += p3 + p7;
      unsigned A = pkrtz(p0, p1);
      unsigned C = pkrtz(p2, p3);
      unsigned B = pkrtz(p4, p5);
      unsigned D = pkrtz(p6, p7);
      asm("v_permlane32_swap_b32 %0, %1" : "+v"(A), "+v"(B));
      asm("v_permlane32_swap_b32 %0, %1" : "+v"(C), "+v"(D));
      u32x4 wv = { A, C, B, D };
      pa[kt*2 + half] = __builtin_bit_cast(h8, wv);
    }
  }

#pragma unroll
  for (int s2 = 0; s2 < 4; ++s2) {
    h8 vf0 = *(const h8*)&Vc[(0*32 + l31)*64 + ((s2*16 + hi*8) ^ swz)];
    h8 vf1 = *(const h8*)&Vc[(1*32 + l31)*64 + ((s2*16 + hi*8) ^ swz)];
    __builtin_amdgcn_s_setprio(1);
    o[0] = MFMA32(pa[s2], vf0, o[0]);
    o[1] = MFMA32(pa[s2], vf1, o[1]);
    __builtin_amdgcn_s_setprio(0);
  }
}

__global__ __launch_bounds__(256, 4)
void attn11_kernel(const f16* __restrict__ Qh, const f16* __restrict__ Kh,
                   const f16* __restrict__ Vt, f16* __restrict__ AO)
{
  const int id = blockIdx.x;
  const int b    = (id & 7) | ((id >> 7) << 3);
  const int qblk = (id >> 3) & 15;

  const int t = threadIdx.x;
  const int w = t >> 6, lane = t & 63;
  const int l31 = lane & 31, hi = lane >> 5;

  const f16* Qb = Qh + (size_t)b * L_SEQ * HDIM;
  const f16* Kb = Kh + (size_t)b * L_SEQ * HDIM;
  const f16* Vb = Vt + (size_t)b * (size_t)HDIM * L_SEQ;

  __shared__ f16 Ks[2][64*64];
  __shared__ f16 Vs[2][64*64];

  const int q0 = qblk * 128 + w * 32;

  h8 qf[4];
#pragma unroll
  for (int s = 0; s < 4; ++s)
    qf[s] = *(const h8*)&Qb[(size_t)(q0 + l31) * HDIM + s*16 + hi*8];

  const int srow = lane >> 3;
  const int scol = 8 * ((lane & 7) ^ srow);
  const int r0   = w*16 + srow;
  const f16* gK0 = Kb + (size_t)(r0    ) * HDIM + scol;
  const f16* gK1 = Kb + (size_t)(r0 + 8) * HDIM + scol;
  const f16* gV0 = Vb + (size_t)(r0    ) * L_SEQ + scol;
  const f16* gV1 = Vb + (size_t)(r0 + 8) * L_SEQ + scol;
  const int ldsw = w * 1024;

  f32x16 o[2] = {};
  float psum[4] = { 0.f, 0.f, 0.f, 0.f };

  glds16(gK0, &Ks[0][ldsw]);
  glds16(gK1, &Ks[0][ldsw + 512]);
  glds16(gV0, &Vs[0][ldsw]);
  glds16(gV1, &Vs[0][ldsw + 512]);
  __syncthreads();

#pragma unroll 1
  for (int j0 = 0; j0 < L_SEQ; j0 += 128) {
    {
      const int jn = (j0 + 64) & (L_SEQ - 1);
      glds16(gK0 + (size_t)jn * HDIM, &Ks[1][ldsw]);
      glds16(gK1 + (size_t)jn * HDIM, &Ks[1][ldsw + 512]);
      glds16(gV0 + jn, &Vs[1][ldsw]);
      glds16(gV1 + jn, &Vs[1][ldsw + 512]);
      attn11_step(&Ks[0][0], &Vs[0][0], qf, o, psum, l31, hi);
      __syncthreads();
    }
    {
      const int jn = (j0 + 128) & (L_SEQ - 1);
      glds16(gK0 + (size_t)jn * HDIM, &Ks[0][ldsw]);
      glds16(gK1 + (size_t)jn * HDIM, &Ks[0][ldsw + 512]);
      glds16(gV0 + jn, &Vs[0][ldsw]);
      glds16(gV1 + jn, &Vs[0][ldsw + 512]);
      attn11_step(&Ks[1][0], &Vs[1][0], qf, o, psum, l31, hi);
      __syncthreads();
    }
  }

  float ssum = (psum[0] + psum[1]) + (psum[2] + psum[3]);
  ssum += __shfl_xor(ssum, 32);
  const float inv = 1.0f / ssum;

  const int nn = b >> 4, h = b & 15;
#pragma unroll
  for (int r = 0; r < 16; ++r) {
    const int qrow = (r & 3) + 8 * (r >> 2) + 4 * hi;
    const float iv = __shfl(inv, qrow);
    const int lr = q0 + qrow;
#pragma unroll
    for (int dt = 0; dt < 2; ++dt)
      AO[((size_t)lr * NBATCH + nn) * EMB + h*HDIM + dt*32 + l31] =
          (f16)(o[dt][r] * iv);
  }
}

// ---------------- launch ----------------
extern "C" void kernel_launch(void* const* d_in, const int* in_sizes, int n_in,
                              void* d_out, int out_size, void* d_ws, size_t ws_size,
                              hipStream_t stream) {
  const float* query = (const float*)d_in[0];
  const float* key   = (const float*)d_in[1];
  const float* value = (const float*)d_in[2];
  const float* in_w  = (const float*)d_in[3];
  const float* in_b  = (const float*)d_in[4];
  const float* out_w = (const float*)d_in[5];
  const float* out_b = (const float*)d_in[6];
  float* out = (float*)d_out;

  char* ws = (char*)d_ws;
  size_t offH  = 0;
  size_t offX  = offH  + (size_t)3 * BH * L_SEQ * HDIM * 2;
  size_t offW  = offX  + (size_t)3 * MROWS * EMB * 2;
  size_t offWo = offW  + (size_t)3 * EMB * EMB * 2;
  size_t offAO = offWo + (size_t)EMB * EMB * 2;
  f16* Hbase = (f16*)(ws + offH);
  f16* Xb    = (f16*)(ws + offX);
  f16* Wb    = (f16*)(ws + offW);
  f16* Wob   = (f16*)(ws + offWo);
  f16* AOb   = (f16*)(ws + offAO);
  f16* Vtb   = Xb;

  hipLaunchKernelGGL(convert_w_kernel, dim3(1024), dim3(256), 0, stream,
                     in_w, out_w, Wb, Wob);

  hipLaunchKernelGGL(gemm_qkv, dim3(1536), dim3(256), 0, stream,
                     query, key, value, Wb, in_b, Hbase);

  f16* Vh = Hbase + (size_t)2 * BH * L_SEQ * HDIM;
  hipLaunchKernelGGL(vtrans_kernel, dim3(L_SEQ/32, BH), dim3(256), 0, stream, Vh, Vtb);

  hipLaunchKernelGGL(attn11_kernel, dim3(L_SEQ/128 * BH), dim3(256), 0, stream,
                     Hbase,
                     Hbase + (size_t)BH * L_SEQ * HDIM,
                     Vtb, AOb);

  hipLaunchKernelGGL(gemm_out, dim3(512), dim3(256), 0, stream,
                     AOb, Wob, out_b, out);
}

// Round 17
// 219.609 us; speedup vs baseline: 1.1362x; 1.0052x over previous
//
#include <hip/hip_runtime.h>

using f16 = _Float16;
typedef _Float16 h8 __attribute__((ext_vector_type(8)));
typedef _Float16 h4 __attribute__((ext_vector_type(4)));
typedef float f32x4 __attribute__((ext_vector_type(4)));
typedef float f32x16 __attribute__((ext_vector_type(16)));
typedef unsigned u32x4 __attribute__((ext_vector_type(4)));

constexpr int L_SEQ  = 2048;
constexpr int NBATCH = 4;
constexpr int EMB    = 1024;
constexpr int NHEAD  = 16;
constexpr int HDIM   = 64;
constexpr int BH     = NBATCH * NHEAD;   // 64 head-batches
constexpr int MROWS  = L_SEQ * NBATCH;   // 8192

// Q pre-scale: 1/sqrt(HD) * log2(e)  (softmax done in exp2 domain)
#define QSCALE (0.125f * 1.44269504088896341f)

__device__ __forceinline__ void glds16(const void* g, void* l) {
  __builtin_amdgcn_global_load_lds(
      (const __attribute__((address_space(1))) void*)g,
      (__attribute__((address_space(3))) void*)l, 16, 0, 0);
}

__device__ __forceinline__ f32x16 MFMA32(h8 a, h8 b, f32x16 c) {
  return __builtin_amdgcn_mfma_f32_32x32x16_f16(a, b, c, 0, 0, 0);
}
__device__ __forceinline__ unsigned pkrtz(float x, float y) {
  auto t = __builtin_amdgcn_cvt_pkrtz(x, y);   // __fp16 ext_vector(2)
  return __builtin_bit_cast(unsigned, t);
}

// ---------------- f32 -> f16 convert (weights only) ----------------
__global__ __launch_bounds__(256)
void convert_w_kernel(const float* __restrict__ w, const float* __restrict__ wo,
                      f16* __restrict__ wb, f16* __restrict__ wob) {
  const int NW  = 3 * EMB * EMB / 4;
  const int NWO = EMB * EMB / 4;
  const int total = NW + NWO;
  int i = blockIdx.x * blockDim.x + threadIdx.x;
  const int stride = gridDim.x * blockDim.x;
  for (; i < total; i += stride) {
    const float* s; f16* d; int j;
    if (i < NW) { s = w;  d = wb;  j = i;      }
    else        { s = wo; d = wob; j = i - NW; }
    float4 t = reinterpret_cast<const float4*>(s)[j];
    h4 o = { (f16)t.x, (f16)t.y, (f16)t.z, (f16)t.w };
    reinterpret_cast<h4*>(d)[j] = o;
  }
}

// ---------------- in-proj GEMM, f32 A, 3-stage counted-vmcnt pipeline ----------------
// B tile now bank-swizzled: LDS[row][s] holds logical[row][s ^ ((row>>1)&3)].
__global__ __launch_bounds__(256)
void gemm_qkv(const float* __restrict__ qin, const float* __restrict__ kin,
              const float* __restrict__ vin, const f16* __restrict__ Btbase,
              const float* __restrict__ biasbase, f16* __restrict__ Hbase)
{
  const int id = blockIdx.x;
  const int x   = id & 7;            // XCD
  const int bnI = (id >> 3) & 7;     // column tile, varies fastest per XCD
  const int bmG = x + 8 * (id >> 6); // global row panel 0..191
  const int z   = bmG >> 6;          // 0..2 (q/k/v)
  const int bm  = (bmG & 63) * 128;
  const int bn  = bnI * 128;

  const float* A = (z == 0) ? qin : (z == 1) ? kin : vin;
  const f16* Bt = Btbase + (size_t)z * EMB * EMB;
  const float* bias = biasbase + (size_t)z * EMB;

  const int t = threadIdx.x;
  const int w = t >> 6, lane = t & 63;
  const int wr = w >> 1, wc = w & 1;
  const int l16 = lane & 15, g = lane >> 4;

  __shared__ float Asf[3][128 * 32];   // 3 x 16 KB, slot-XOR swizzled (^row&7)
  __shared__ f16 Bs[3][128][32];       // 3 x 8 KB, slot-XOR swizzled (^(row>>1)&3)

  f32x4 acc[4][4] = {};

  const int srow8 = lane >> 3;                  // 0..7
  const int sslot = (lane & 7) ^ srow8;         // pre-swizzled source slot (A, f32)
  const float* gA = &A[(size_t)(bm + w*32 + srow8) * EMB + sslot * 4];

  const int sr   = lane >> 2;
  const int sc8  = 8 * ((lane & 3) ^ ((lane >> 3) & 3));  // pre-swizzled source (B, f16)
  const f16* gB = &Bt[(size_t)(bn + w*32 + sr) * EMB + sc8];

  auto stage = [&](int buf, int k0) {
#pragma unroll
    for (int r = 0; r < 4; ++r)
      glds16(gA + (size_t)r*8*EMB + k0, &Asf[buf][(w*32 + r*8) * 32]);
    glds16(gB + k0, &Bs[buf][w*32][0]);
    glds16(gB + (size_t)16*EMB + k0, &Bs[buf][w*32 + 16][0]);
  };

  const int bswz = (g ^ ((l16 >> 1) & 3)) * 8;   // B read slot (swizzled)

  auto compute = [&](int buf) {
    h8 af[4], bfr[4];
#pragma unroll
    for (int m = 0; m < 4; ++m) {
      const int row = wr*64 + m*16 + l16;
      const int r7 = row & 7;
      f32x4 lo = *(const f32x4*)&Asf[buf][row*32 + (((g*2    ) ^ r7) << 2)];
      f32x4 hi = *(const f32x4*)&Asf[buf][row*32 + (((g*2 + 1) ^ r7) << 2)];
      u32x4 u = { pkrtz(lo[0], lo[1]), pkrtz(lo[2], lo[3]),
                  pkrtz(hi[0], hi[1]), pkrtz(hi[2], hi[3]) };
      af[m] = __builtin_bit_cast(h8, u);
    }
#pragma unroll
    for (int n = 0; n < 4; ++n)
      bfr[n] = *(const h8*)&Bs[buf][wc*64 + n*16 + l16][bswz];
    __builtin_amdgcn_s_setprio(1);
#pragma unroll
    for (int m = 0; m < 4; ++m)
#pragma unroll
      for (int n = 0; n < 4; ++n)
        acc[m][n] = __builtin_amdgcn_mfma_f32_16x16x32_f16(af[m], bfr[n], acc[m][n], 0, 0, 0);
    __builtin_amdgcn_s_setprio(0);
  };

  // prologue: stage iters 0 and 1
  stage(0, 0);
  stage(1, 32);

  int cur = 0;
#pragma unroll 1
  for (int i = 0; i < 31; ++i) {
    asm volatile("s_waitcnt vmcnt(6)" ::: "memory");
    __builtin_amdgcn_sched_barrier(0);
    __builtin_amdgcn_s_barrier();
    __builtin_amdgcn_sched_barrier(0);
    if (i < 30) {
      const int nb = (cur + 2 >= 3) ? cur - 1 : cur + 2;
      stage(nb, (i + 2) * 32);
    }
    compute(cur);
    cur = (cur == 2) ? 0 : cur + 1;
  }
  asm volatile("s_waitcnt vmcnt(0)" ::: "memory");
  __builtin_amdgcn_sched_barrier(0);
  __builtin_amdgcn_s_barrier();
  __builtin_amdgcn_sched_barrier(0);
  compute(cur);

#pragma unroll
  for (int m = 0; m < 4; ++m) {
#pragma unroll
    for (int n = 0; n < 4; ++n) {
      const int col = bn + wc*64 + n*16 + l16;
      const float bv = bias[col];
#pragma unroll
      for (int r = 0; r < 4; ++r) {
        const int row = bm + wr*64 + m*16 + g*4 + r;
        float v = acc[m][n][r] + bv;
        if (z == 0) v *= QSCALE;
        const int l = row >> 2, nn = row & 3;
        const int h = col >> 6, hd = col & 63;
        Hbase[(((size_t)z * BH + nn * NHEAD + h) * L_SEQ + l) * HDIM + hd] = (f16)v;
      }
    }
  }
}

// ---------------- out-proj GEMM (f16 A), dbuf, A+B bank-swizzled ----------------
__global__ __launch_bounds__(256)
void gemm_out(const f16* __restrict__ A, const f16* __restrict__ Bt,
              const float* __restrict__ bias, float* __restrict__ Fout)
{
  const int id = blockIdx.x;
  const int x   = id & 7;
  const int bnI = (id >> 3) & 7;
  const int bmG = x + 8 * (id >> 6);   // 0..63
  const int bm  = bmG * 128;
  const int bn  = bnI * 128;

  const int t = threadIdx.x;
  const int w = t >> 6, lane = t & 63;
  const int wr = w >> 1, wc = w & 1;
  const int l16 = lane & 15, g = lane >> 4;

  __shared__ f16 As[2][128][32];
  __shared__ f16 Bs[2][128][32];

  f32x4 acc[4][4] = {};

  const int sr  = lane >> 2;
  const int sc8 = 8 * ((lane & 3) ^ ((lane >> 3) & 3));   // pre-swizzled source
  const f16* gA = &A [(size_t)(bm + w*32 + sr) * EMB + sc8];
  const f16* gB = &Bt[(size_t)(bn + w*32 + sr) * EMB + sc8];

  glds16(gA, &As[0][w*32][0]);
  glds16(gA + (size_t)16*EMB, &As[0][w*32 + 16][0]);
  glds16(gB, &Bs[0][w*32][0]);
  glds16(gB + (size_t)16*EMB, &Bs[0][w*32 + 16][0]);
  __syncthreads();

  const int fswz = (g ^ ((l16 >> 1) & 3)) * 8;   // fragment read slot (swizzled)

#pragma unroll 1
  for (int i = 0; i < 32; ++i) {
    const int cur = i & 1;
    if (i < 31) {
      const int k0 = (i + 1) * 32;
      glds16(gA + k0, &As[cur ^ 1][w*32][0]);
      glds16(gA + (size_t)16*EMB + k0, &As[cur ^ 1][w*32 + 16][0]);
      glds16(gB + k0, &Bs[cur ^ 1][w*32][0]);
      glds16(gB + (size_t)16*EMB + k0, &Bs[cur ^ 1][w*32 + 16][0]);
    }

    h8 af[4], bfr[4];
#pragma unroll
    for (int m = 0; m < 4; ++m) af[m]  = *(const h8*)&As[cur][wr*64 + m*16 + l16][fswz];
#pragma unroll
    for (int n = 0; n < 4; ++n) bfr[n] = *(const h8*)&Bs[cur][wc*64 + n*16 + l16][fswz];
    __builtin_amdgcn_s_setprio(1);
#pragma unroll
    for (int m = 0; m < 4; ++m)
#pragma unroll
      for (int n = 0; n < 4; ++n)
        acc[m][n] = __builtin_amdgcn_mfma_f32_16x16x32_f16(af[m], bfr[n], acc[m][n], 0, 0, 0);
    __builtin_amdgcn_s_setprio(0);
    __syncthreads();
  }

#pragma unroll
  for (int m = 0; m < 4; ++m) {
#pragma unroll
    for (int n = 0; n < 4; ++n) {
      const int col = bn + wc*64 + n*16 + l16;
      const float bv = bias[col];
#pragma unroll
      for (int r = 0; r < 4; ++r) {
        const int row = bm + wr*64 + m*16 + g*4 + r;
        Fout[(size_t)row * EMB + col] = acc[m][n][r] + bv;
      }
    }
  }
}

// ---------------- V transpose: [BH][L][HD] -> [BH][HD][L] ----------------
__global__ __launch_bounds__(256)
void vtrans_kernel(const f16* __restrict__ V, f16* __restrict__ Vt) {
  const int b = blockIdx.y;
  const int t = threadIdx.x;
  const int d = t & 63;
  const int l0 = (blockIdx.x * 4 + (t >> 6)) * 8;
  const f16* Vb = V  + (size_t)b * L_SEQ * HDIM;
  f16* Vtb      = Vt + (size_t)b * L_SEQ * HDIM;
  h8 v;
#pragma unroll
  for (int i = 0; i < 8; ++i) v[i] = Vb[(size_t)(l0 + i) * HDIM + d];
  *(h8*)&Vtb[(size_t)d * L_SEQ + l0] = v;
}

// ---------------- Flash attention v11 (register-slim, unchanged) ----------------
__device__ __forceinline__ void attn11_step(
    const f16* __restrict__ Kc, const f16* __restrict__ Vc,
    const h8 (&qf)[4],
    f32x16 (&o)[2], float (&psum)[4],
    int l31, int hi)
{
  const int swz = (l31 & 7) << 3;

  h8 pa[4];
#pragma unroll
  for (int kt = 0; kt < 2; ++kt) {
    f32x16 acc = {};
    __builtin_amdgcn_s_setprio(1);
#pragma unroll
    for (int s = 0; s < 4; ++s) {
      h8 kf = *(const h8*)&Kc[(kt*32 + l31)*64 + ((s*16 + hi*8) ^ swz)];
      acc = MFMA32(kf, qf[s], acc);
    }
    __builtin_amdgcn_s_setprio(0);

#pragma unroll
    for (int half = 0; half < 2; ++half) {
      float p0 = __builtin_amdgcn_exp2f(acc[half*8+0]);
      float p1 = __builtin_amdgcn_exp2f(acc[half*8+1]);
      float p2 = __builtin_amdgcn_exp2f(acc[half*8+2]);
      float p3 = __builtin_amdgcn_exp2f(acc[half*8+3]);
      float p4 = __builtin_amdgcn_exp2f(acc[half*8+4]);
      float p5 = __builtin_amdgcn_exp2f(acc[half*8+5]);
      float p6 = __builtin_amdgcn_exp2f(acc[half*8+6]);
      float p7 = __builtin_amdgcn_exp2f(acc[half*8+7]);
      psum[0] += p0 + p4;
      psum[1] += p1 + p5;
      psum[2] += p2 + p6;
      psum[3] += p3 + p7;
      unsigned A = pkrtz(p0, p1);
      unsigned C = pkrtz(p2, p3);
      unsigned B = pkrtz(p4, p5);
      unsigned D = pkrtz(p6, p7);
      asm("v_permlane32_swap_b32 %0, %1" : "+v"(A), "+v"(B));
      asm("v_permlane32_swap_b32 %0, %1" : "+v"(C), "+v"(D));
      u32x4 wv = { A, C, B, D };
      pa[kt*2 + half] = __builtin_bit_cast(h8, wv);
    }
  }

#pragma unroll
  for (int s2 = 0; s2 < 4; ++s2) {
    h8 vf0 = *(const h8*)&Vc[(0*32 + l31)*64 + ((s2*16 + hi*8) ^ swz)];
    h8 vf1 = *(const h8*)&Vc[(1*32 + l31)*64 + ((s2*16 + hi*8) ^ swz)];
    __builtin_amdgcn_s_setprio(1);
    o[0] = MFMA32(pa[s2], vf0, o[0]);
    o[1] = MFMA32(pa[s2], vf1, o[1]);
    __builtin_amdgcn_s_setprio(0);
  }
}

__global__ __launch_bounds__(256, 4)
void attn11_kernel(const f16* __restrict__ Qh, const f16* __restrict__ Kh,
                   const f16* __restrict__ Vt, f16* __restrict__ AO)
{
  const int id = blockIdx.x;
  const int b    = (id & 7) | ((id >> 7) << 3);
  const int qblk = (id >> 3) & 15;

  const int t = threadIdx.x;
  const int w = t >> 6, lane = t & 63;
  const int l31 = lane & 31, hi = lane >> 5;

  const f16* Qb = Qh + (size_t)b * L_SEQ * HDIM;
  const f16* Kb = Kh + (size_t)b * L_SEQ * HDIM;
  const f16* Vb = Vt + (size_t)b * (size_t)HDIM * L_SEQ;

  __shared__ f16 Ks[2][64*64];
  __shared__ f16 Vs[2][64*64];

  const int q0 = qblk * 128 + w * 32;

  h8 qf[4];
#pragma unroll
  for (int s = 0; s < 4; ++s)
    qf[s] = *(const h8*)&Qb[(size_t)(q0 + l31) * HDIM + s*16 + hi*8];

  const int srow = lane >> 3;
  const int scol = 8 * ((lane & 7) ^ srow);
  const int r0   = w*16 + srow;
  const f16* gK0 = Kb + (size_t)(r0    ) * HDIM + scol;
  const f16* gK1 = Kb + (size_t)(r0 + 8) * HDIM + scol;
  const f16* gV0 = Vb + (size_t)(r0    ) * L_SEQ + scol;
  const f16* gV1 = Vb + (size_t)(r0 + 8) * L_SEQ + scol;
  const int ldsw = w * 1024;

  f32x16 o[2] = {};
  float psum[4] = { 0.f, 0.f, 0.f, 0.f };

  glds16(gK0, &Ks[0][ldsw]);
  glds16(gK1, &Ks[0][ldsw + 512]);
  glds16(gV0, &Vs[0][ldsw]);
  glds16(gV1, &Vs[0][ldsw + 512]);
  __syncthreads();

#pragma unroll 1
  for (int j0 = 0; j0 < L_SEQ; j0 += 128) {
    {
      const int jn = (j0 + 64) & (L_SEQ - 1);
      glds16(gK0 + (size_t)jn * HDIM, &Ks[1][ldsw]);
      glds16(gK1 + (size_t)jn * HDIM, &Ks[1][ldsw + 512]);
      glds16(gV0 + jn, &Vs[1][ldsw]);
      glds16(gV1 + jn, &Vs[1][ldsw + 512]);
      attn11_step(&Ks[0][0], &Vs[0][0], qf, o, psum, l31, hi);
      __syncthreads();
    }
    {
      const int jn = (j0 + 128) & (L_SEQ - 1);
      glds16(gK0 + (size_t)jn * HDIM, &Ks[0][ldsw]);
      glds16(gK1 + (size_t)jn * HDIM, &Ks[0][ldsw + 512]);
      glds16(gV0 + jn, &Vs[0][ldsw]);
      glds16(gV1 + jn, &Vs[0][ldsw + 512]);
      attn11_step(&Ks[1][0], &Vs[1][0], qf, o, psum, l31, hi);
      __syncthreads();
    }
  }

  float ssum = (psum[0] + psum[1]) + (psum[2] + psum[3]);
  ssum += __shfl_xor(ssum, 32);
  const float inv = 1.0f / ssum;

  const int nn = b >> 4, h = b & 15;
#pragma unroll
  for (int r = 0; r < 16; ++r) {
    const int qrow = (r & 3) + 8 * (r >> 2) + 4 * hi;
    const float iv = __shfl(inv, qrow);
    const int lr = q0 + qrow;
#pragma unroll
    for (int dt = 0; dt < 2; ++dt)
      AO[((size_t)lr * NBATCH + nn) * EMB + h*HDIM + dt*32 + l31] =
          (f16)(o[dt][r] * iv);
  }
}

// ---------------- launch ----------------
extern "C" void kernel_launch(void* const* d_in, const int* in_sizes, int n_in,
                              void* d_out, int out_size, void* d_ws, size_t ws_size,
                              hipStream_t stream) {
  const float* query = (const float*)d_in[0];
  const float* key   = (const float*)d_in[1];
  const float* value = (const float*)d_in[2];
  const float* in_w  = (const float*)d_in[3];
  const float* in_b  = (const float*)d_in[4];
  const float* out_w = (const float*)d_in[5];
  const float* out_b = (const float*)d_in[6];
  float* out = (float*)d_out;

  char* ws = (char*)d_ws;
  size_t offH  = 0;
  size_t offX  = offH  + (size_t)3 * BH * L_SEQ * HDIM * 2;
  size_t offW  = offX  + (size_t)3 * MROWS * EMB * 2;
  size_t offWo = offW  + (size_t)3 * EMB * EMB * 2;
  size_t offAO = offWo + (size_t)EMB * EMB * 2;
  f16* Hbase = (f16*)(ws + offH);
  f16* Xb    = (f16*)(ws + offX);
  f16* Wb    = (f16*)(ws + offW);
  f16* Wob   = (f16*)(ws + offWo);
  f16* AOb   = (f16*)(ws + offAO);
  f16* Vtb   = Xb;

  hipLaunchKernelGGL(convert_w_kernel, dim3(1024), dim3(256), 0, stream,
                     in_w, out_w, Wb, Wob);

  hipLaunchKernelGGL(gemm_qkv, dim3(1536), dim3(256), 0, stream,
                     query, key, value, Wb, in_b, Hbase);

  f16* Vh = Hbase + (size_t)2 * BH * L_SEQ * HDIM;
  hipLaunchKernelGGL(vtrans_kernel, dim3(L_SEQ/32, BH), dim3(256), 0, stream, Vh, Vtb);

  hipLaunchKernelGGL(attn11_kernel, dim3(L_SEQ/128 * BH), dim3(256), 0, stream,
                     Hbase,
                     Hbase + (size_t)BH * L_SEQ * HDIM,
                     Vtb, AOb);

  hipLaunchKernelGGL(gemm_out, dim3(512), dim3(256), 0, stream,
                     AOb, Wob, out_b, out);
}